// Round 3
// baseline (550.489 us; speedup 1.0000x reference)
//
#include <hip/hip_runtime.h>
#include <hip/hip_bf16.h>

// CostVolume: out[b,h,w,i0*9+j0] = mean_c( prv[b,h,w,c] * nxt[b,h+i0-4,w+j0-4,c] )
// B=16, H=W=128, C=192, r=4, d=9, 81 offsets.
// Inputs: float32. Output: float32 (reference output dtype; threshold = 2% of max|ref|).
//
// Strategy: per 4x4 prv tile, Gram matrix G[16 prv px][144 halo px (12x12)] via
// mfma_f32_16x16x32_bf16. fp32 inputs downconverted to bf16 fragments in-register
// (RNE); error ~6e-4 absmax, well under the 7.85e-3 threshold. 81/144 of G is
// useful; epilogue gathers through LDS with flat-indexed coalesced fp32 stores.
// One wave per block.

typedef __attribute__((ext_vector_type(8))) short short8;
typedef __attribute__((ext_vector_type(4))) float float4v;

#define HH 128
#define WW 128
#define CC 192
#define ROWP 20   // LDS col stride (16 rows padded to 20 floats)

static __device__ __forceinline__ unsigned short f2bf(float f) {
    unsigned int u = __builtin_bit_cast(unsigned int, f);
    u += 0x7FFFu + ((u >> 16) & 1u);   // RNE
    return (unsigned short)(u >> 16);
}

// Load 8 contiguous fp32 and convert to a bf16 MFMA fragment (RNE).
static __device__ __forceinline__ short8 cvt8(const float* __restrict__ p) {
    float4v f0 = *reinterpret_cast<const float4v*>(p);
    float4v f1 = *reinterpret_cast<const float4v*>(p + 4);
    short8 r;
#pragma unroll
    for (int i = 0; i < 4; ++i) r[i]     = (short)f2bf(f0[i]);
#pragma unroll
    for (int i = 0; i < 4; ++i) r[i + 4] = (short)f2bf(f1[i]);
    return r;
}

__global__ __launch_bounds__(64) void costvol_gram_kernel(
    const float* __restrict__ prv,
    const float* __restrict__ nxt,
    float* __restrict__ out)
{
    const int lane = threadIdx.x;        // 0..63
    const int m    = lane & 15;          // MFMA 16-index (A row / B col / D col)
    const int q    = lane >> 4;          // quad
    const int wt = blockIdx.x, ht = blockIdx.y, b = blockIdx.z;
    const int h0 = ht * 4, w0 = wt * 4;
    const int pr = m >> 2, pc = m & 3;   // prv pixel within 4x4 tile (pixel index = m)

    // A operand: lane holds prv(h0+pr, w0+pc, kk*32 + q*8 + j), j=0..7
    const float* prv_base =
        prv + (((size_t)b * HH + (h0 + pr)) * WW + (w0 + pc)) * CC + q * 8;

    // B operand set s: halo pixel n = s*16 + m -> (nr, nc) in 12x12 halo
    const float* nxt_img = nxt + (size_t)b * HH * WW * CC;
    const float* nxt_ptr[9];
    bool ok[9];
#pragma unroll
    for (int s = 0; s < 9; ++s) {
        int n  = s * 16 + m;
        int nr = n / 12, nc = n % 12;
        int hh = h0 - 4 + nr, ww = w0 - 4 + nc;
        ok[s] = (hh >= 0) && (hh < HH) && (ww >= 0) && (ww < WW);
        int hc = hh < 0 ? 0 : (hh > HH - 1 ? HH - 1 : hh);
        int wc = ww < 0 ? 0 : (ww > WW - 1 ? WW - 1 : ww);
        nxt_ptr[s] = nxt_img + (((size_t)hc * WW) + wc) * CC + q * 8;
    }

    float4v acc[9];
#pragma unroll
    for (int s = 0; s < 9; ++s) acc[s] = (float4v){0.f, 0.f, 0.f, 0.f};

    // K loop: 192 channels = 6 chunks of 32
#pragma unroll
    for (int kk = 0; kk < 6; ++kk) {
        short8 a = cvt8(prv_base + kk * 32);
#pragma unroll
        for (int s = 0; s < 9; ++s) {
            short8 bf;
            if (ok[s]) bf = cvt8(nxt_ptr[s] + kk * 32);
            else       bf = (short8)0;
            acc[s] = __builtin_amdgcn_mfma_f32_16x16x32_bf16(a, bf, acc[s], 0, 0, 0);
        }
    }

    // Epilogue: G[halo col][prv row]; lane (q,m), set s holds D[prv=q*4+reg][halo=s*16+m].
    __shared__ float G[144 * ROWP];
#pragma unroll
    for (int s = 0; s < 9; ++s) {
        int col = s * 16 + m;
        *reinterpret_cast<float4v*>(&G[col * ROWP + q * 4]) = acc[s];
    }
    __syncthreads();

    const float scale = 1.0f / 192.0f;
    // Flat-indexed coalesced stores: 16 pixels x 81 offsets = 1296 floats.
    // Pixel rows (4 px * 81 = 324 floats) are contiguous in out.
    float* out_tile_row[4];
#pragma unroll
    for (int rr = 0; rr < 4; ++rr)
        out_tile_row[rr] = out + (((size_t)b * HH + (h0 + rr)) * WW + w0) * 81;

#pragma unroll
    for (int t = 0; t < 21; ++t) {
        int f = t * 64 + lane;           // 0..1343; valid while f < 1296
        if (f < 1296) {
            int p  = f / 81;             // tile pixel index 0..15
            int k  = f - p * 81;         // offset index 0..80
            int i0 = k / 9, j0 = k - i0 * 9;
            int ppr = p >> 2, ppc = p & 3;
            int col = (ppr + i0) * 12 + (ppc + j0);
            float v = G[col * ROWP + p] * scale;
            out_tile_row[ppr][ppc * 81 + k] = v;
        }
    }
}

extern "C" void kernel_launch(void* const* d_in, const int* in_sizes, int n_in,
                              void* d_out, int out_size, void* d_ws, size_t ws_size,
                              hipStream_t stream) {
    const float* prv = (const float*)d_in[0];
    const float* nxt = (const float*)d_in[1];
    float* out = (float*)d_out;
    dim3 grid(WW / 4, HH / 4, 16);   // w-tiles, h-tiles, batch
    dim3 block(64);
    hipLaunchKernelGGL(costvol_gram_kernel, grid, block, 0, stream, prv, nxt, out);
}